// Round 1
// baseline (319.178 us; speedup 1.0000x reference)
//
#include <hip/hip_runtime.h>
#include <hip/hip_bf16.h>

#define EPS 1e-7f

// Sizes (fixed per reference): B=64, Lc=512, La=64, Dc=Da=1024
#define B   64
#define LC  512
#define LA  64
#define D   1024
#define D4  256          // D / 4
#define CHUNKS 32        // l-chunks per b in ctx_pass
#define ROWS_PER_CHUNK (LC / CHUNKS)   // 16

// ---------------------------------------------------------------------------
// K1: asp_avg[b][e] = mean over La of asp_text[b][l][e]
// grid (4, 64), block 64. Each block covers 64 float4s (256 floats) of e.
__global__ void k_asp_mean(const float* __restrict__ A, float* __restrict__ avg) {
    int b  = blockIdx.y;
    int f4 = blockIdx.x * 64 + threadIdx.x;           // float4 index 0..255
    const float4* base = reinterpret_cast<const float4*>(A + (size_t)b * LA * D);
    float sx = 0.f, sy = 0.f, sz = 0.f, sw = 0.f;
    #pragma unroll 8
    for (int l = 0; l < LA; ++l) {
        float4 v = base[l * D4 + f4];
        sx += v.x; sy += v.y; sz += v.z; sw += v.w;
    }
    const float inv = 1.0f / (float)LA;
    float4 o; o.x = sx * inv; o.y = sy * inv; o.z = sz * inv; o.w = sw * inv;
    reinterpret_cast<float4*>(avg)[b * D4 + f4] = o;
}

// ---------------------------------------------------------------------------
// K2/K4: V[b][d] = sum_e W[d][e] * X[b][e]      W:[1024][1024], X:[64][1024]
// grid 256, block 256 (4 waves). Wave w owns d = bid*4 + w; W row in regs;
// X rows staged in LDS one b at a time (W read exactly once from HBM).
__global__ void k_matvec_rows(const float* __restrict__ W, const float* __restrict__ X,
                              float* __restrict__ V) {
    __shared__ float xrow[D];
    int w    = threadIdx.x >> 6;
    int lane = threadIdx.x & 63;
    int d    = blockIdx.x * 4 + w;

    float4 wr[4];
    const float4* Wrow = reinterpret_cast<const float4*>(W + (size_t)d * D);
    #pragma unroll
    for (int k = 0; k < 4; ++k) wr[k] = Wrow[lane + 64 * k];

    for (int b = 0; b < B; ++b) {
        __syncthreads();
        reinterpret_cast<float4*>(xrow)[threadIdx.x] =
            reinterpret_cast<const float4*>(X + (size_t)b * D)[threadIdx.x];
        __syncthreads();
        float p = 0.f;
        #pragma unroll
        for (int k = 0; k < 4; ++k) {
            float4 x = reinterpret_cast<const float4*>(xrow)[lane + 64 * k];
            p += wr[k].x * x.x + wr[k].y * x.y + wr[k].z * x.z + wr[k].w * x.w;
        }
        #pragma unroll
        for (int m = 1; m < 64; m <<= 1) p += __shfl_xor(p, m, 64);
        if (lane == 0) V[b * D + d] = p;
    }
}

// ---------------------------------------------------------------------------
// K3: fused single pass over context.
// grid (CHUNKS, B), block 64 (one wave). Per row l: s = <row, v_c[b]>,
// e = exp(tanh(s + cb[l])); accumulate e*row (attend numerator), row (mean),
// e (denominator). Partials per (b,chunk) to workspace.
__global__ void k_ctx_pass(const float* __restrict__ C, const float* __restrict__ vc,
                           const float* __restrict__ cb,
                           float* __restrict__ pacc, float* __restrict__ psum,
                           float* __restrict__ pesum) {
    int b    = blockIdx.y;
    int c    = blockIdx.x;
    int lane = threadIdx.x;

    float4 vr[4];
    const float4* vcr = reinterpret_cast<const float4*>(vc + (size_t)b * D);
    #pragma unroll
    for (int k = 0; k < 4; ++k) vr[k] = vcr[lane + 64 * k];

    float4 acc[4], sct[4];
    #pragma unroll
    for (int k = 0; k < 4; ++k) {
        acc[k].x = acc[k].y = acc[k].z = acc[k].w = 0.f;
        sct[k].x = sct[k].y = sct[k].z = sct[k].w = 0.f;
    }
    float esum = 0.f;

    const float4* Cb = reinterpret_cast<const float4*>(C + (size_t)b * LC * D);
    for (int r = 0; r < ROWS_PER_CHUNK; ++r) {
        int l = c * ROWS_PER_CHUNK + r;
        const float4* row = Cb + (size_t)l * D4;
        float4 x[4];
        #pragma unroll
        for (int k = 0; k < 4; ++k) x[k] = row[lane + 64 * k];
        float p = 0.f;
        #pragma unroll
        for (int k = 0; k < 4; ++k)
            p += x[k].x * vr[k].x + x[k].y * vr[k].y + x[k].z * vr[k].z + x[k].w * vr[k].w;
        #pragma unroll
        for (int m = 1; m < 64; m <<= 1) p += __shfl_xor(p, m, 64);
        float e = expf(tanhf(p + cb[l]));
        esum += e;
        #pragma unroll
        for (int k = 0; k < 4; ++k) {
            acc[k].x += e * x[k].x; acc[k].y += e * x[k].y;
            acc[k].z += e * x[k].z; acc[k].w += e * x[k].w;
            sct[k].x += x[k].x; sct[k].y += x[k].y;
            sct[k].z += x[k].z; sct[k].w += x[k].w;
        }
    }

    int pidx = b * CHUNKS + c;
    float4* pa = reinterpret_cast<float4*>(pacc + (size_t)pidx * D);
    float4* ps = reinterpret_cast<float4*>(psum + (size_t)pidx * D);
    #pragma unroll
    for (int k = 0; k < 4; ++k) { pa[lane + 64 * k] = acc[k]; ps[lane + 64 * k] = sct[k]; }
    if (lane == 0) pesum[pidx] = esum;
}

// ---------------------------------------------------------------------------
// K3b: reduce partials -> attend_context (into d_out cols [0,1024)) and
// context_avg (to ws). grid 64, block 256 (thread t owns float4 index t).
__global__ void k_ctx_reduce(const float* __restrict__ pacc, const float* __restrict__ psum,
                             const float* __restrict__ pesum,
                             float* __restrict__ out, float* __restrict__ ctx_avg) {
    int b = blockIdx.x;
    int t = threadIdx.x;
    float ax = 0.f, ay = 0.f, az = 0.f, aw = 0.f;
    float sx = 0.f, sy = 0.f, sz = 0.f, sw = 0.f;
    for (int c = 0; c < CHUNKS; ++c) {
        const float4* pa = reinterpret_cast<const float4*>(pacc + (size_t)(b * CHUNKS + c) * D);
        const float4* ps = reinterpret_cast<const float4*>(psum + (size_t)(b * CHUNKS + c) * D);
        float4 va = pa[t], vs = ps[t];
        ax += va.x; ay += va.y; az += va.z; aw += va.w;
        sx += vs.x; sy += vs.y; sz += vs.z; sw += vs.w;
    }
    float es = 0.f;
    for (int c = 0; c < CHUNKS; ++c) es += pesum[b * CHUNKS + c];
    float inv = 1.0f / (es + EPS);
    float4 o; o.x = ax * inv; o.y = ay * inv; o.z = az * inv; o.w = aw * inv;
    reinterpret_cast<float4*>(out)[b * (2 * D4) + t] = o;      // attend_context
    const float invL = 1.0f / (float)LC;
    float4 m; m.x = sx * invL; m.y = sy * invL; m.z = sz * invL; m.w = sw * invL;
    reinterpret_cast<float4*>(ctx_avg)[b * D4 + t] = m;
}

// ---------------------------------------------------------------------------
// K5: aspect branch. grid 64 (one block per b), block 256 (4 waves, 16 rows ea).
// a_t_sum = sum_l exp(tanh(<asp_text[b,l], v_t[b]> + ab[l])) + EPS
// attend_asp[b,d] = a_t_sum * La * asp_avg[b,d]   (faithful to reference bug)
__global__ void k_asp_pass(const float* __restrict__ A, const float* __restrict__ vt,
                           const float* __restrict__ ab, const float* __restrict__ asp_avg,
                           float* __restrict__ out) {
    __shared__ float wsum[4];
    int b    = blockIdx.x;
    int w    = threadIdx.x >> 6;
    int lane = threadIdx.x & 63;

    float4 vr[4];
    const float4* vtr = reinterpret_cast<const float4*>(vt + (size_t)b * D);
    #pragma unroll
    for (int k = 0; k < 4; ++k) vr[k] = vtr[lane + 64 * k];

    float esum = 0.f;
    const float4* Ab = reinterpret_cast<const float4*>(A + (size_t)b * LA * D);
    for (int r = 0; r < 16; ++r) {
        int l = w * 16 + r;
        const float4* row = Ab + (size_t)l * D4;
        float p = 0.f;
        #pragma unroll
        for (int k = 0; k < 4; ++k) {
            float4 x = row[lane + 64 * k];
            p += x.x * vr[k].x + x.y * vr[k].y + x.z * vr[k].z + x.w * vr[k].w;
        }
        #pragma unroll
        for (int m = 1; m < 64; m <<= 1) p += __shfl_xor(p, m, 64);
        esum += expf(tanhf(p + ab[l]));
    }
    if (lane == 0) wsum[w] = esum;
    __syncthreads();
    float scale = (wsum[0] + wsum[1] + wsum[2] + wsum[3] + EPS) * (float)LA;
    float4 av = reinterpret_cast<const float4*>(asp_avg)[b * D4 + threadIdx.x];
    float4 o; o.x = av.x * scale; o.y = av.y * scale; o.z = av.z * scale; o.w = av.w * scale;
    reinterpret_cast<float4*>(out)[b * (2 * D4) + D4 + threadIdx.x] = o;   // attend_asp
}

// ---------------------------------------------------------------------------
extern "C" void kernel_launch(void* const* d_in, const int* in_sizes, int n_in,
                              void* d_out, int out_size, void* d_ws, size_t ws_size,
                              hipStream_t stream) {
    const float* context   = (const float*)d_in[0];
    const float* asp_text  = (const float*)d_in[1];
    const float* context_w = (const float*)d_in[2];
    const float* context_b = (const float*)d_in[3];
    const float* aspect_w  = (const float*)d_in[4];
    const float* aspect_b  = (const float*)d_in[5];
    float* out = (float*)d_out;
    float* ws  = (float*)d_ws;

    // workspace layout (floats)
    float* asp_avg = ws;                       // 64*1024
    float* v_c     = asp_avg + B * D;          // 64*1024
    float* ctx_avg = v_c + B * D;              // 64*1024
    float* v_t     = ctx_avg + B * D;          // 64*1024
    float* pacc    = v_t + B * D;              // 2048*1024
    float* psum    = pacc + B * CHUNKS * D;    // 2048*1024
    float* pesum   = psum + B * CHUNKS * D;    // 2048

    k_asp_mean<<<dim3(4, B), 64, 0, stream>>>(asp_text, asp_avg);
    k_matvec_rows<<<D / 4, 256, 0, stream>>>(context_w, asp_avg, v_c);
    k_ctx_pass<<<dim3(CHUNKS, B), 64, 0, stream>>>(context, v_c, context_b,
                                                   pacc, psum, pesum);
    k_ctx_reduce<<<B, 256, 0, stream>>>(pacc, psum, pesum, out, ctx_avg);
    k_matvec_rows<<<D / 4, 256, 0, stream>>>(aspect_w, ctx_avg, v_t);
    k_asp_pass<<<B, 256, 0, stream>>>(asp_text, v_t, aspect_b, asp_avg, out);
}

// Round 3
// 264.645 us; speedup vs baseline: 1.2061x; 1.2061x over previous
//
#include <hip/hip_runtime.h>
#include <hip/hip_bf16.h>

#define EPS 1e-7f

// Sizes (fixed per reference): B=64, Lc=512, La=64, Dc=Da=1024
#define B   64
#define LC  512
#define LA  64
#define D   1024
#define D4  256          // D / 4 (float4 count per row)
#define ROWS 16          // rows per block in split-D passes
#define CCHUNKS (LC / ROWS)   // 32 context chunks per b

// ---------------------------------------------------------------------------
// K1: per-(b, s) partial row-sums of asp_text. grid (4, B), block 256.
// Thread t owns float4 column t; sums 16 rows -> P[(b*4+s)*D4 + t].
__global__ void k_asp_psum(const float* __restrict__ A, float* __restrict__ P) {
    int b = blockIdx.y, s = blockIdx.x, t = threadIdx.x;
    const float4* Ab = reinterpret_cast<const float4*>(A + (size_t)b * LA * D);
    float sx = 0.f, sy = 0.f, sz = 0.f, sw = 0.f;
    #pragma unroll
    for (int r = 0; r < ROWS; ++r) {
        float4 v = Ab[(s * ROWS + r) * D4 + t];
        sx += v.x; sy += v.y; sz += v.z; sw += v.w;
    }
    float4 o; o.x = sx; o.y = sy; o.z = sz; o.w = sw;
    reinterpret_cast<float4*>(P)[(b * 4 + s) * D4 + t] = o;
}

// K1b: asp_avg = (sum of 4 partials) / La. grid (B), block 256.
__global__ void k_asp_combine(const float* __restrict__ P, float* __restrict__ avg) {
    int b = blockIdx.x, t = threadIdx.x;
    const float4* P4 = reinterpret_cast<const float4*>(P);
    float sx = 0.f, sy = 0.f, sz = 0.f, sw = 0.f;
    #pragma unroll
    for (int s = 0; s < 4; ++s) {
        float4 v = P4[(b * 4 + s) * D4 + t];
        sx += v.x; sy += v.y; sz += v.z; sw += v.w;
    }
    const float inv = 1.0f / (float)LA;
    float4 o; o.x = sx * inv; o.y = sy * inv; o.z = sz * inv; o.w = sw * inv;
    reinterpret_cast<float4*>(avg)[b * D4 + t] = o;
}

// ---------------------------------------------------------------------------
// K2/K4: V[b][d] = sum_e W[d][e] * X[b][e].  No LDS, no barriers.
// grid (128, 4), block 256. Wave w owns 2 W-rows in registers; streams 16 b's
// of X from global (X is tiny -> L2 resident).
__global__ void k_matvec(const float* __restrict__ W, const float* __restrict__ X,
                         float* __restrict__ V) {
    int w    = threadIdx.x >> 6;
    int lane = threadIdx.x & 63;
    int d0   = (blockIdx.x * 4 + w) * 2;      // [0, 1024) even
    int b0   = blockIdx.y * 16;

    float4 w0[4], w1[4];
    const float4* Wr0 = reinterpret_cast<const float4*>(W + (size_t)d0 * D);
    const float4* Wr1 = reinterpret_cast<const float4*>(W + (size_t)(d0 + 1) * D);
    #pragma unroll
    for (int k = 0; k < 4; ++k) { w0[k] = Wr0[lane + 64 * k]; w1[k] = Wr1[lane + 64 * k]; }

    #pragma unroll 4
    for (int bb = 0; bb < 16; ++bb) {
        int b = b0 + bb;
        const float4* Xr = reinterpret_cast<const float4*>(X + (size_t)b * D);
        float p0 = 0.f, p1 = 0.f;
        #pragma unroll
        for (int k = 0; k < 4; ++k) {
            float4 x = Xr[lane + 64 * k];
            p0 += x.x * w0[k].x + x.y * w0[k].y + x.z * w0[k].z + x.w * w0[k].w;
            p1 += x.x * w1[k].x + x.y * w1[k].y + x.z * w1[k].z + x.w * w1[k].w;
        }
        #pragma unroll
        for (int m = 1; m < 64; m <<= 1) {
            p0 += __shfl_xor(p0, m, 64);
            p1 += __shfl_xor(p1, m, 64);
        }
        if (lane == 0) { V[b * D + d0] = p0; V[b * D + d0 + 1] = p1; }
    }
}

// ---------------------------------------------------------------------------
// K3: fused context pass, split-D. grid (32, B), block 256 (4 waves).
// Wave w owns D-quarter [w*256, w*256+256); 16 rows held in registers.
// Phase 1: quarter-dots -> LDS; Phase 2: e = exp(tanh(s+cb)); Phase 3:
// e-weighted accumulate + plain row-sum from registers; per-chunk partials out.
__global__ __launch_bounds__(256, 4)
void k_ctx_pass(const float* __restrict__ C, const float* __restrict__ vc,
                const float* __restrict__ cb,
                float* __restrict__ pacc, float* __restrict__ psum,
                float* __restrict__ pesum) {
    __shared__ float sdot[ROWS][4];
    __shared__ float se[ROWS];
    int b = blockIdx.y, c = blockIdx.x;
    int w    = threadIdx.x >> 6;
    int lane = threadIdx.x & 63;
    int f4   = w * 64 + lane;                 // float4 index within row [0,256)

    float4 vr = reinterpret_cast<const float4*>(vc + (size_t)b * D)[f4];

    const float4* Cb = reinterpret_cast<const float4*>(C + ((size_t)b * LC + c * ROWS) * D);
    float4 x[ROWS];
    #pragma unroll
    for (int r = 0; r < ROWS; ++r) x[r] = Cb[r * D4 + f4];   // 16 independent loads

    #pragma unroll
    for (int r = 0; r < ROWS; ++r) {
        float p = x[r].x * vr.x + x[r].y * vr.y + x[r].z * vr.z + x[r].w * vr.w;
        #pragma unroll
        for (int m = 1; m < 64; m <<= 1) p += __shfl_xor(p, m, 64);
        if (lane == 0) sdot[r][w] = p;
    }
    __syncthreads();
    if (threadIdx.x < ROWS) {
        int r = threadIdx.x;
        float s = sdot[r][0] + sdot[r][1] + sdot[r][2] + sdot[r][3];
        se[r] = expf(tanhf(s + cb[c * ROWS + r]));
    }
    __syncthreads();

    float4 acc = {0.f, 0.f, 0.f, 0.f}, sct = {0.f, 0.f, 0.f, 0.f};
    #pragma unroll
    for (int r = 0; r < ROWS; ++r) {
        float e = se[r];
        acc.x += e * x[r].x; acc.y += e * x[r].y; acc.z += e * x[r].z; acc.w += e * x[r].w;
        sct.x += x[r].x;     sct.y += x[r].y;     sct.z += x[r].z;     sct.w += x[r].w;
    }
    int pidx = b * CCHUNKS + c;
    reinterpret_cast<float4*>(pacc)[pidx * D4 + f4] = acc;
    reinterpret_cast<float4*>(psum)[pidx * D4 + f4] = sct;
    if (w == 0) {
        float e2 = (lane < ROWS) ? se[lane] : 0.f;
        #pragma unroll
        for (int m = 1; m < 64; m <<= 1) e2 += __shfl_xor(e2, m, 64);
        if (lane == 0) pesum[pidx] = e2;
    }
}

// ---------------------------------------------------------------------------
// K3b: reduce partials -> attend_context (out cols [0,1024)) + context_avg.
// grid (4, B), block 64. Block (q,b) owns float4 range [q*64, q*64+64).
__global__ void k_ctx_reduce(const float* __restrict__ pacc, const float* __restrict__ psum,
                             const float* __restrict__ pesum,
                             float* __restrict__ out, float* __restrict__ ctx_avg) {
    int b = blockIdx.y, q = blockIdx.x;
    int f4 = q * 64 + threadIdx.x;
    float ax = 0.f, ay = 0.f, az = 0.f, aw = 0.f;
    float sx = 0.f, sy = 0.f, sz = 0.f, sw = 0.f;
    const float4* pa = reinterpret_cast<const float4*>(pacc);
    const float4* ps = reinterpret_cast<const float4*>(psum);
    #pragma unroll 8
    for (int c = 0; c < CCHUNKS; ++c) {
        float4 va = pa[(b * CCHUNKS + c) * D4 + f4];
        float4 vs = ps[(b * CCHUNKS + c) * D4 + f4];
        ax += va.x; ay += va.y; az += va.z; aw += va.w;
        sx += vs.x; sy += vs.y; sz += vs.z; sw += vs.w;
    }
    float es = 0.f;
    #pragma unroll 8
    for (int c = 0; c < CCHUNKS; ++c) es += pesum[b * CCHUNKS + c];
    float inv = 1.0f / (es + EPS);
    float4 o; o.x = ax * inv; o.y = ay * inv; o.z = az * inv; o.w = aw * inv;
    reinterpret_cast<float4*>(out)[b * (2 * D4) + f4] = o;          // attend_context
    const float invL = 1.0f / (float)LC;
    float4 m; m.x = sx * invL; m.y = sy * invL; m.z = sz * invL; m.w = sw * invL;
    reinterpret_cast<float4*>(ctx_avg)[b * D4 + f4] = m;
}

// ---------------------------------------------------------------------------
// K5a: aspect scores, split-D like K3 (no accumulate needed).
// grid (4, B), block 256. Block (q,b) handles rows [q*16, q*16+16).
// Writes pesumA[b*4+q] = sum_r exp(tanh(<row, v_t> + ab)).
__global__ void k_asp_score(const float* __restrict__ A, const float* __restrict__ vt,
                            const float* __restrict__ ab, float* __restrict__ pesumA) {
    __shared__ float sdot[ROWS][4];
    __shared__ float se[ROWS];
    int b = blockIdx.y, q = blockIdx.x;
    int w    = threadIdx.x >> 6;
    int lane = threadIdx.x & 63;
    int f4   = w * 64 + lane;

    float4 vr = reinterpret_cast<const float4*>(vt + (size_t)b * D)[f4];
    const float4* Ab = reinterpret_cast<const float4*>(A + ((size_t)b * LA + q * ROWS) * D);
    #pragma unroll
    for (int r = 0; r < ROWS; ++r) {
        float4 x = Ab[r * D4 + f4];
        float p = x.x * vr.x + x.y * vr.y + x.z * vr.z + x.w * vr.w;
        #pragma unroll
        for (int m = 1; m < 64; m <<= 1) p += __shfl_xor(p, m, 64);
        if (lane == 0) sdot[r][w] = p;
    }
    __syncthreads();
    if (threadIdx.x < ROWS) {
        int r = threadIdx.x;
        float s = sdot[r][0] + sdot[r][1] + sdot[r][2] + sdot[r][3];
        se[r] = expf(tanhf(s + ab[q * ROWS + r]));
    }
    __syncthreads();
    if (w == 0) {
        float e2 = (lane < ROWS) ? se[lane] : 0.f;
        #pragma unroll
        for (int m = 1; m < 64; m <<= 1) e2 += __shfl_xor(e2, m, 64);
        if (lane == 0) pesumA[b * 4 + q] = e2;
    }
}

// K5b: attend_asp = (sum_q pesumA + EPS) * La * asp_avg -> out cols [1024,2048).
// grid (B), block 256.
__global__ void k_asp_scale(const float* __restrict__ pesumA, const float* __restrict__ asp_avg,
                            float* __restrict__ out) {
    int b = blockIdx.x, t = threadIdx.x;
    float es = pesumA[b * 4 + 0] + pesumA[b * 4 + 1] + pesumA[b * 4 + 2] + pesumA[b * 4 + 3];
    float scale = (es + EPS) * (float)LA;
    float4 av = reinterpret_cast<const float4*>(asp_avg)[b * D4 + t];
    float4 o; o.x = av.x * scale; o.y = av.y * scale; o.z = av.z * scale; o.w = av.w * scale;
    reinterpret_cast<float4*>(out)[b * (2 * D4) + D4 + t] = o;
}

// ---------------------------------------------------------------------------
extern "C" void kernel_launch(void* const* d_in, const int* in_sizes, int n_in,
                              void* d_out, int out_size, void* d_ws, size_t ws_size,
                              hipStream_t stream) {
    const float* context   = (const float*)d_in[0];
    const float* asp_text  = (const float*)d_in[1];
    const float* context_w = (const float*)d_in[2];
    const float* context_b = (const float*)d_in[3];
    const float* aspect_w  = (const float*)d_in[4];
    const float* aspect_b  = (const float*)d_in[5];
    float* out = (float*)d_out;
    float* ws  = (float*)d_ws;

    // workspace layout (floats)
    float* asp_avg = ws;                        // 64*1024
    float* v_c     = asp_avg + B * D;           // 64*1024
    float* ctx_avg = v_c + B * D;               // 64*1024
    float* v_t     = ctx_avg + B * D;           // 64*1024
    float* pacc    = v_t + B * D;               // 2048*1024
    float* psum    = pacc + (size_t)B * CCHUNKS * D;  // 2048*1024
    float* pesum   = psum + (size_t)B * CCHUNKS * D;  // 2048
    float* pesumA  = pesum + B * CCHUNKS;       // 256
    float* Ppart   = pesumA + B * 4;            // 4*64*1024

    k_asp_psum   <<<dim3(4, B),  256, 0, stream>>>(asp_text, Ppart);
    k_asp_combine<<<B,           256, 0, stream>>>(Ppart, asp_avg);
    k_matvec     <<<dim3(128, 4),256, 0, stream>>>(context_w, asp_avg, v_c);
    k_ctx_pass   <<<dim3(CCHUNKS, B), 256, 0, stream>>>(context, v_c, context_b,
                                                        pacc, psum, pesum);
    k_ctx_reduce <<<dim3(4, B),  64,  0, stream>>>(pacc, psum, pesum, out, ctx_avg);
    k_matvec     <<<dim3(128, 4),256, 0, stream>>>(aspect_w, ctx_avg, v_t);
    k_asp_score  <<<dim3(4, B),  256, 0, stream>>>(asp_text, v_t, aspect_b, pesumA);
    k_asp_scale  <<<B,           256, 0, stream>>>(pesumA, asp_avg, out);
}